// Round 19
// baseline (249.418 us; speedup 1.0000x reference)
//
#include <hip/hip_runtime.h>
#include <math.h>

#define N_NODES 100000
#define N_EDGES 800000
#define HID 128
#define HEADS 4
#define HD 32

// 1/sqrt(32) * log2(e), folded into K projection; logits feed exp2 directly
#define KSCALE_L2E 0.2550348554422384f

#define PROJ_PERS  512    // persistent proj blocks (2/CU), 512 thr each
#define PROJ_TILES 782    // ceil(N_NODES/128)
#define FILL_BLOCKS 1563  // ceil(N_EDGES/512)

typedef __attribute__((ext_vector_type(8))) short short8;
typedef __attribute__((ext_vector_type(4))) float f32x4;
typedef _Float16 h2 __attribute__((ext_vector_type(2)));
typedef __fp16 hf2 __attribute__((ext_vector_type(2)));   // cvt_pkrtz return type

__device__ __forceinline__ unsigned int f2bf(float f) {
    unsigned int u = __float_as_uint(f);
    u += 0x7FFFu + ((u >> 16) & 1u);
    return (u >> 16) & 0xFFFFu;   // RNE round to bf16
}
__device__ __forceinline__ h2 u2h(unsigned int u) { return __builtin_bit_cast(h2, u); }
__device__ __forceinline__ unsigned int h2u(h2 h) { return __builtin_bit_cast(unsigned int, h); }
__device__ __forceinline__ unsigned int h2u(hf2 h) { return __builtin_bit_cast(unsigned int, h); }

// ---------------------------------------------------------------------------
// prep: blocks 0..31 convert W fp32 -> bf16 transposed chunks [m][n][kc]
// (for LDS staging); remaining blocks histogram edge destinations.
// ---------------------------------------------------------------------------
__global__ __launch_bounds__(256) void prep(
    const float* __restrict__ Wq, const float* __restrict__ Wk,
    const float* __restrict__ Wv, const float* __restrict__ Ws,
    uint4* __restrict__ wtbf, const int* __restrict__ ei,
    int* __restrict__ deg)
{
    const int b = blockIdx.x;
    if (b < 32) {
        int idx = b * 256 + threadIdx.x;        // [4][128][16]
        int m = idx >> 11, n = (idx >> 4) & 127, kc = idx & 15;
        const float* W = (m == 0) ? Wq : (m == 1) ? Wk : (m == 2) ? Wv : Ws;
        unsigned int h[8];
        #pragma unroll
        for (int j = 0; j < 8; ++j) h[j] = f2bf(W[(kc * 8 + j) * HID + n]);
        uint4 o;
        o.x = h[0] | (h[1] << 16);
        o.y = h[2] | (h[3] << 16);
        o.z = h[4] | (h[5] << 16);
        o.w = h[6] | (h[7] << 16);
        wtbf[idx] = o;
    } else {
        int e = (b - 32) * 256 + threadIdx.x;
        if (e < N_EDGES) atomicAdd(&deg[ei[N_EDGES + e]], 1);
    }
}

// ---------------------------------------------------------------------------
// CSR scan: hierarchical (49 blk local -> per-block offset add).
// ---------------------------------------------------------------------------
__global__ __launch_bounds__(256) void scan_local(const int* __restrict__ deg,
                                                  int* __restrict__ rowptr,
                                                  int* __restrict__ bsum)
{
    __shared__ int wsums[4];
    const int b = blockIdx.x, t = threadIdx.x, lane = t & 63, wid = t >> 6;
    const int base = b * 2048 + t * 8;
    int v[8], s = 0;
    #pragma unroll
    for (int j = 0; j < 8; ++j) {
        int i = base + j;
        v[j] = (i < N_NODES) ? deg[i] : 0;
        s += v[j];
    }
    const int tsum = s;
    int x = tsum;
    #pragma unroll
    for (int off = 1; off < 64; off <<= 1) {
        int t2 = __shfl_up(x, off);
        if (lane >= off) x += t2;
    }
    if (lane == 63) wsums[wid] = x;
    __syncthreads();
    int wpre = 0;
    #pragma unroll
    for (int ww = 0; ww < 4; ++ww) { if (ww < wid) wpre += wsums[ww]; }
    int run = wpre + x - tsum;
    #pragma unroll
    for (int j = 0; j < 8; ++j) {
        int i = base + j;
        if (i < N_NODES) rowptr[i] = run;
        run += v[j];
    }
    if (t == 0) bsum[b] = wsums[0] + wsums[1] + wsums[2] + wsums[3];
}

__global__ __launch_bounds__(256) void add_off(int* __restrict__ rowptr,
                                               const int* __restrict__ bsum)
{
    __shared__ int offs;
    const int t = threadIdx.x;
    const int tgt = blockIdx.x >> 3;       // 2048-node groups / 256-node blocks
    if (t < 64) {
        int v = (t < tgt) ? bsum[t] : 0;
        #pragma unroll
        for (int off = 1; off < 64; off <<= 1) v += __shfl_xor(v, off);
        if (t == 0) offs = v;
    }
    __syncthreads();
    int i = blockIdx.x * 256 + t;
    if (i < N_NODES) rowptr[i] += offs;
    if (blockIdx.x == 0 && t == 0) rowptr[N_NODES] = N_EDGES;
}

// ---------------------------------------------------------------------------
// Fused: blocks 0..PROJ_PERS-1 = PERSISTENT MFMA projections (512 thr, 64 KB
// LDS): stage W-pair ONCE, then grid-stride over 128-row tiles BARRIER-FREE;
// one barrier, restage second pair, second pass. Remaining blocks = CSR fill
// (atomicSub countdown on deg -> deg ends zero), packing around proj.
// ---------------------------------------------------------------------------
__global__ __launch_bounds__(512) void fill_proj(
    const int* __restrict__ ei, const int* __restrict__ rowptr,
    int* __restrict__ deg, int* __restrict__ csr_src,
    const float* __restrict__ x, const uint4* __restrict__ wtbf,
    const float* __restrict__ bq, const float* __restrict__ bk,
    const float* __restrict__ bv, const float* __restrict__ bs,
    unsigned short* __restrict__ Qh, unsigned short* __restrict__ KVh,
    unsigned short* __restrict__ Sh)
{
    __shared__ uint4 wt[4096];          // 64 KB: one W PAIR at a time

    if (blockIdx.x >= PROJ_PERS) {
        int e = (blockIdx.x - PROJ_PERS) * 512 + threadIdx.x;
        if (e < N_EDGES) {
            int src = ei[e], dst = ei[N_EDGES + e];
            int old = atomicSub(&deg[dst], 1);
            csr_src[rowptr[dst] + old - 1] = src;
        }
        return;
    }

    const int tid  = threadIdx.x;
    const int lane = tid & 63;
    const int w    = tid >> 6;          // 0..7
    const int r    = lane & 15;
    const int kg   = lane >> 4;

    #pragma unroll
    for (int pair = 0; pair < 2; ++pair) {
        if (pair == 1) __syncthreads();          // all tiles of prior pair done
        // stage this pair's two W matrices: 4096 uint4 (64 KB), swizzled
        #pragma unroll
        for (int it = 0; it < 8; ++it) {
            int cid = it * 512 + tid;            // [mh][n][kc] within pair
            int kc = cid & 15, n = (cid >> 4) & 127;
            wt[(cid & ~15) | (kc ^ (n & 7))] = wtbf[pair * 4096 + cid];
        }
        __syncthreads();

        // barrier-free tile loop: each wave owns 16 rows of each tile
        for (int tile = blockIdx.x; tile < PROJ_TILES; tile += PROJ_PERS) {
            const int grow = tile * 128 + w * 16 + r;
            short8 afr[4];
            #pragma unroll
            for (int s = 0; s < 4; ++s) {
                float4 a = make_float4(0.f, 0.f, 0.f, 0.f);
                float4 b = make_float4(0.f, 0.f, 0.f, 0.f);
                if (grow < N_NODES) {
                    const float4* p = (const float4*)(x + (size_t)grow * HID + (s * 4 + kg) * 8);
                    a = p[0]; b = p[1];
                }
                uint4 o;
                o.x = f2bf(a.x) | (f2bf(a.y) << 16);
                o.y = f2bf(a.z) | (f2bf(a.w) << 16);
                o.z = f2bf(b.x) | (f2bf(b.y) << 16);
                o.w = f2bf(b.z) | (f2bf(b.w) << 16);
                afr[s] = *(short8*)&o;
            }

            #pragma unroll
            for (int mh = 0; mh < 2; ++mh) {
                const int m = pair * 2 + mh;
                const float* bias = (m == 0) ? bq : (m == 1) ? bk : (m == 2) ? bv : bs;
                const uint4* wtm = wt + mh * 2048;
                #pragma unroll
                for (int nt = 0; nt < 8; ++nt) {
                    const int nrow = nt * 16 + r;
                    const uint4* wrow = wtm + nrow * 16;
                    f32x4 acc;
                    acc[0]=0.f; acc[1]=0.f; acc[2]=0.f; acc[3]=0.f;
                    #pragma unroll
                    for (int s = 0; s < 4; ++s) {
                        short8 bfr = *(const short8*)&wrow[(s * 4 + kg) ^ (nrow & 7)];
                        acc = __builtin_amdgcn_mfma_f32_16x16x32_bf16(bfr, afr[s], acc, 0, 0, 0);
                    }
                    if (grow < N_NODES) {
                        const int col = nt * 16 + kg * 4;
                        float4 bi = *(const float4*)(bias + col);
                        float vx = acc[0] + bi.x, vy = acc[1] + bi.y;
                        float vz = acc[2] + bi.z, vw = acc[3] + bi.w;
                        if (m == 1) { vx *= KSCALE_L2E; vy *= KSCALE_L2E;
                                      vz *= KSCALE_L2E; vw *= KSCALE_L2E; }
                        uint2 pk;
                        pk.x = h2u(__builtin_amdgcn_cvt_pkrtz(vx, vy));
                        pk.y = h2u(__builtin_amdgcn_cvt_pkrtz(vz, vw));
                        unsigned short* dst =
                            (m == 0) ? (Qh + (size_t)grow * HID + col) :
                            (m == 1) ? (KVh + (size_t)grow * 256 + col) :
                            (m == 2) ? (KVh + (size_t)grow * 256 + 128 + col) :
                                       (Sh + (size_t)grow * HID + col);
                        *(uint2*)dst = pk;
                    }
                }
            }
        }
    }
}

// ---------------------------------------------------------------------------
// Fused per-node attention (FP16 packed math): one wave per node; FOUR
// 16-lane edge slots (8 dims/lane), prefetch DISTANCE 2 (3 KV buffers in
// rotation -> 12 gathers in flight per wave). Direct exp2 (K pre-scaled).
// Slot merge on packed regs; skip + LayerNorm fused.
// ---------------------------------------------------------------------------
__global__ __launch_bounds__(256) void node_attn(
    const int* __restrict__ rowptr, const int* __restrict__ csr_src,
    const unsigned short* __restrict__ Qh, const unsigned short* __restrict__ KVh,
    const unsigned short* __restrict__ Sh,
    const float* __restrict__ gamma, const float* __restrict__ beta,
    float* __restrict__ out)
{
    const int tid  = threadIdx.x;
    const int lane = tid & 63;
    const int node = blockIdx.x * 4 + (tid >> 6);
    if (node >= N_NODES) return;

    const int l16 = lane & 15;
    const int es  = lane >> 4;            // edge slot 0..3
    const int j8  = l16 * 8;              // dims j8..j8+7; head = l16>>2

    const int r0 = rowptr[node], r1 = rowptr[node + 1];

    uint4 qp = *(const uint4*)(Qh + (size_t)node * HID + j8);
    const h2 qh0 = u2h(qp.x), qh1 = u2h(qp.y), qh2 = u2h(qp.z), qh3 = u2h(qp.w);

    float den = 0.f;
    h2 ac0 = {0, 0}, ac1 = {0, 0}, ac2 = {0, 0}, ac3 = {0, 0};

    int pA = r0 + es;                     // current
    int pB = pA + 4;                      // +1 iteration
    uint4 kA = {0,0,0,0}, vA = {0,0,0,0}, kB = {0,0,0,0}, vB = {0,0,0,0};
    if (pA < r1) {
        const unsigned short* base = KVh + (size_t)csr_src[pA] * 256;
        kA = *(const uint4*)(base + j8);
        vA = *(const uint4*)(base + 128 + j8);
    }
    if (pB < r1) {
        const unsigned short* base = KVh + (size_t)csr_src[pB] * 256;
        kB = *(const uint4*)(base + j8);
        vB = *(const uint4*)(base + 128 + j8);
    }

    for (int it = r0; it < r1; it += 4) {
        // prefetch distance-2 iteration
        const int pn = pA + 8;
        uint4 kn = {0,0,0,0}, vn = {0,0,0,0};
        if (pn < r1) {
            const unsigned short* base = KVh + (size_t)csr_src[pn] * 256;
            kn = *(const uint4*)(base + j8);
            vn = *(const uint4*)(base + 128 + j8);
        }

        // packed fp16 dot (4 x v_pk_fma_f16) then f32 finish
        h2 d = qh0 * u2h(kA.x);
        d += qh1 * u2h(kA.y);
        d += qh2 * u2h(kA.z);
        d += qh3 * u2h(kA.w);
        float t = (float)d.x + (float)d.y;
        t += __shfl_xor(t, 1);
        t += __shfl_xor(t, 2);              // 4-lane head group complete

        float e = (pA < r1) ? __builtin_amdgcn_exp2f(t) : 0.f;
        den += e;
        _Float16 eh = (_Float16)e;
        h2 e2 = {eh, eh};
        ac0 += e2 * u2h(vA.x);
        ac1 += e2 * u2h(vA.y);
        ac2 += e2 * u2h(vA.z);
        ac3 += e2 * u2h(vA.w);

        // rotate buffers
        pA = pB; pB = pn;
        kA = kB; vA = vB; kB = kn; vB = vn;
    }

    // merge the 4 edge slots (lanes ^16, ^32) on packed regs
    #pragma unroll
    for (int msk = 16; msk <= 32; msk <<= 1) {
        den += __shfl_xor(den, msk);
        ac0 += u2h(__shfl_xor(h2u(ac0), msk));
        ac1 += u2h(__shfl_xor(h2u(ac1), msk));
        ac2 += u2h(__shfl_xor(h2u(ac2), msk));
        ac3 += u2h(__shfl_xor(h2u(ac3), msk));
    }

    float inv = 1.0f / (den + 1e-16f);
    uint4 sp = *(const uint4*)(Sh + (size_t)node * HID + j8);
    const h2 s0 = u2h(sp.x), s1 = u2h(sp.y), s2 = u2h(sp.z), s3 = u2h(sp.w);
    float o0 = (float)ac0.x * inv + (float)s0.x, o1 = (float)ac0.y * inv + (float)s0.y;
    float o2 = (float)ac1.x * inv + (float)s1.x, o3 = (float)ac1.y * inv + (float)s1.y;
    float o4 = (float)ac2.x * inv + (float)s2.x, o5 = (float)ac2.y * inv + (float)s2.y;
    float o6 = (float)ac3.x * inv + (float)s3.x, o7 = (float)ac3.y * inv + (float)s3.y;

    // LayerNorm reduce over 16 lanes (all slots hold identical data now)
    float sum = (o0 + o1) + (o2 + o3) + (o4 + o5) + (o6 + o7);
    float sq  = o0*o0 + o1*o1 + o2*o2 + o3*o3 + o4*o4 + o5*o5 + o6*o6 + o7*o7;
    #pragma unroll
    for (int off = 1; off < 16; off <<= 1) {
        sum += __shfl_xor(sum, off);
        sq  += __shfl_xor(sq, off);
    }
    float mean = sum * (1.0f / 128.0f);
    float var  = sq * (1.0f / 128.0f) - mean * mean;
    float rstd = rsqrtf(var + 1e-5f);

    if (es == 0) {
        float4 g0 = *(const float4*)(gamma + j8);
        float4 g1 = *(const float4*)(gamma + j8 + 4);
        float4 b0 = *(const float4*)(beta + j8);
        float4 b1 = *(const float4*)(beta + j8 + 4);
        float4 w0, w1;
        w0.x = (o0 - mean) * rstd * g0.x + b0.x;
        w0.y = (o1 - mean) * rstd * g0.y + b0.y;
        w0.z = (o2 - mean) * rstd * g0.z + b0.z;
        w0.w = (o3 - mean) * rstd * g0.w + b0.w;
        w1.x = (o4 - mean) * rstd * g1.x + b1.x;
        w1.y = (o5 - mean) * rstd * g1.y + b1.y;
        w1.z = (o6 - mean) * rstd * g1.z + b1.z;
        w1.w = (o7 - mean) * rstd * g1.w + b1.w;
        float* op = out + (size_t)node * HID + j8;
        *(float4*)op = w0;
        *(float4*)(op + 4) = w1;
    }
}

// ---------------------------------------------------------------------------
extern "C" void kernel_launch(void* const* d_in, const int* in_sizes, int n_in,
                              void* d_out, int out_size, void* d_ws, size_t ws_size,
                              hipStream_t stream) {
    const float* x  = (const float*)d_in[0];
    const int*   ei = (const int*)d_in[1];
    const float* Wq = (const float*)d_in[2];
    const float* bq = (const float*)d_in[3];
    const float* Wk = (const float*)d_in[4];
    const float* bk = (const float*)d_in[5];
    const float* Wv = (const float*)d_in[6];
    const float* bv = (const float*)d_in[7];
    const float* Ws = (const float*)d_in[8];
    const float* bs = (const float*)d_in[9];
    const float* gamma = (const float*)d_in[10];
    const float* beta  = (const float*)d_in[11];
    float* out = (float*)d_out;

    // workspace layout (all fp16 feature buffers)
    unsigned short* Qh  = (unsigned short*)d_ws;               // [N,128]
    unsigned short* KVh = Qh + (size_t)N_NODES * HID;          // [N,256]
    unsigned short* Sh  = KVh + (size_t)N_NODES * 256;         // [N,128]
    uint4* wtbf  = (uint4*)(Sh + (size_t)N_NODES * HID);       // [4*128*16]
    int* deg     = (int*)(wtbf + 4 * 128 * 16);
    int* rowptr  = deg + N_NODES;                              // N+1
    int* csr_src = rowptr + (N_NODES + 1);
    int* bsum    = csr_src + N_EDGES;                          // 64

    hipMemsetAsync(deg, 0, N_NODES * sizeof(int), stream);

    const int eblk = (N_EDGES + 255) / 256;                    // 3125
    prep<<<32 + eblk, 256, 0, stream>>>(Wq, Wk, Wv, Ws, wtbf, ei, deg);

    const int nb = (N_NODES + 2047) / 2048;                    // 49
    scan_local<<<nb, 256, 0, stream>>>(deg, rowptr, bsum);
    add_off<<<(N_NODES + 255) / 256, 256, 0, stream>>>(rowptr, bsum);

    fill_proj<<<PROJ_PERS + FILL_BLOCKS, 512, 0, stream>>>(
        ei, rowptr, deg, csr_src, x, wtbf, bq, bk, bv, bs, Qh, KVh, Sh);

    node_attn<<<(N_NODES + 3) / 4, 256, 0, stream>>>(rowptr, csr_src, Qh, KVh, Sh,
                                                     gamma, beta, out);
}

// Round 20
// 206.123 us; speedup vs baseline: 1.2100x; 1.2100x over previous
//
#include <hip/hip_runtime.h>
#include <math.h>

#define N_NODES 100000
#define N_EDGES 800000
#define HID 128
#define HEADS 4
#define HD 32

// 1/sqrt(32) * log2(e), folded into K projection; logits feed exp2 directly
#define KSCALE_L2E 0.2550348554422384f

#define PROJ_BLOCKS 1563  // ceil(N_NODES/64): 256 thr, 4 waves x 16 rows
#define FILL_BLOCKS 3125  // ceil(N_EDGES/256)

typedef __attribute__((ext_vector_type(8))) short short8;
typedef __attribute__((ext_vector_type(4))) float f32x4;
typedef _Float16 h2 __attribute__((ext_vector_type(2)));
typedef __fp16 hf2 __attribute__((ext_vector_type(2)));   // cvt_pkrtz return type

__device__ __forceinline__ unsigned int f2bf(float f) {
    unsigned int u = __float_as_uint(f);
    u += 0x7FFFu + ((u >> 16) & 1u);
    return (u >> 16) & 0xFFFFu;   // RNE round to bf16
}
__device__ __forceinline__ h2 u2h(unsigned int u) { return __builtin_bit_cast(h2, u); }
__device__ __forceinline__ unsigned int h2u(h2 h) { return __builtin_bit_cast(unsigned int, h); }
__device__ __forceinline__ unsigned int h2u(hf2 h) { return __builtin_bit_cast(unsigned int, h); }

// ---------------------------------------------------------------------------
// prep: blocks 0..31 convert W fp32 -> bf16 FRAGMENT-LINEAR layout
//   wtbf[((m*8+nt)*4+s)*64 + lane] = 8 bf16 of W_m[k=(s*4+kg)*8+j][n=nt*16+r]
//   (lane = kg*16+r) -> each MFMA B-operand is one coalesced 16B/lane load.
// Remaining blocks histogram edge destinations.
// ---------------------------------------------------------------------------
__global__ __launch_bounds__(256) void prep(
    const float* __restrict__ Wq, const float* __restrict__ Wk,
    const float* __restrict__ Wv, const float* __restrict__ Ws,
    uint4* __restrict__ wtbf, const int* __restrict__ ei,
    int* __restrict__ deg)
{
    const int b = blockIdx.x;
    if (b < 32) {
        int idx = b * 256 + threadIdx.x;        // [m][nt][s][lane]
        int lane = idx & 63;
        int s    = (idx >> 6) & 3;
        int nt   = (idx >> 8) & 7;
        int m    = idx >> 11;
        int r    = lane & 15;
        int kg   = lane >> 4;
        const float* W = (m == 0) ? Wq : (m == 1) ? Wk : (m == 2) ? Wv : Ws;
        const int n  = nt * 16 + r;
        const int k0 = (s * 4 + kg) * 8;
        unsigned int h[8];
        #pragma unroll
        for (int j = 0; j < 8; ++j) h[j] = f2bf(W[(k0 + j) * HID + n]);
        uint4 o;
        o.x = h[0] | (h[1] << 16);
        o.y = h[2] | (h[3] << 16);
        o.z = h[4] | (h[5] << 16);
        o.w = h[6] | (h[7] << 16);
        wtbf[idx] = o;
    } else {
        int e = (b - 32) * 256 + threadIdx.x;
        if (e < N_EDGES) atomicAdd(&deg[ei[N_EDGES + e]], 1);
    }
}

// ---------------------------------------------------------------------------
// CSR scan: hierarchical (49 blk local -> per-block offset add).
// ---------------------------------------------------------------------------
__global__ __launch_bounds__(256) void scan_local(const int* __restrict__ deg,
                                                  int* __restrict__ rowptr,
                                                  int* __restrict__ bsum)
{
    __shared__ int wsums[4];
    const int b = blockIdx.x, t = threadIdx.x, lane = t & 63, wid = t >> 6;
    const int base = b * 2048 + t * 8;
    int v[8], s = 0;
    #pragma unroll
    for (int j = 0; j < 8; ++j) {
        int i = base + j;
        v[j] = (i < N_NODES) ? deg[i] : 0;
        s += v[j];
    }
    const int tsum = s;
    int x = tsum;
    #pragma unroll
    for (int off = 1; off < 64; off <<= 1) {
        int t2 = __shfl_up(x, off);
        if (lane >= off) x += t2;
    }
    if (lane == 63) wsums[wid] = x;
    __syncthreads();
    int wpre = 0;
    #pragma unroll
    for (int ww = 0; ww < 4; ++ww) { if (ww < wid) wpre += wsums[ww]; }
    int run = wpre + x - tsum;
    #pragma unroll
    for (int j = 0; j < 8; ++j) {
        int i = base + j;
        if (i < N_NODES) rowptr[i] = run;
        run += v[j];
    }
    if (t == 0) bsum[b] = wsums[0] + wsums[1] + wsums[2] + wsums[3];
}

__global__ __launch_bounds__(256) void add_off(int* __restrict__ rowptr,
                                               const int* __restrict__ bsum)
{
    __shared__ int offs;
    const int t = threadIdx.x;
    const int tgt = blockIdx.x >> 3;       // 2048-node groups / 256-node blocks
    if (t < 64) {
        int v = (t < tgt) ? bsum[t] : 0;
        #pragma unroll
        for (int off = 1; off < 64; off <<= 1) v += __shfl_xor(v, off);
        if (t == 0) offs = v;
    }
    __syncthreads();
    int i = blockIdx.x * 256 + t;
    if (i < N_NODES) rowptr[i] += offs;
    if (blockIdx.x == 0 && t == 0) rowptr[N_NODES] = N_EDGES;
}

// ---------------------------------------------------------------------------
// Fused: blocks 0..PROJ_BLOCKS-1 = MFMA projections, NO LDS / NO BARRIERS:
// W fragments stream L2->registers with explicit +1-step prefetch (wc/wn),
// so MFMAs always consume already-resident fragments. 4 waves x 16 rows.
// Remaining blocks = CSR fill (atomicSub countdown; deg ends zero).
// ---------------------------------------------------------------------------
__global__ __launch_bounds__(256) void fill_proj(
    const int* __restrict__ ei, const int* __restrict__ rowptr,
    int* __restrict__ deg, int* __restrict__ csr_src,
    const float* __restrict__ x, const uint4* __restrict__ wtbf,
    const float* __restrict__ bq, const float* __restrict__ bk,
    const float* __restrict__ bv, const float* __restrict__ bs,
    unsigned short* __restrict__ Qh, unsigned short* __restrict__ KVh,
    unsigned short* __restrict__ Sh)
{
    if (blockIdx.x >= PROJ_BLOCKS) {
        int e = (blockIdx.x - PROJ_BLOCKS) * 256 + threadIdx.x;
        if (e < N_EDGES) {
            int src = ei[e], dst = ei[N_EDGES + e];
            int old = atomicSub(&deg[dst], 1);
            csr_src[rowptr[dst] + old - 1] = src;
        }
        return;
    }

    const int tid  = threadIdx.x;
    const int lane = tid & 63;
    const int w    = tid >> 6;          // 0..3
    const int r    = lane & 15;
    const int kg   = lane >> 4;

    // this wave's 16 x-rows into bf16 fragments
    const int grow = blockIdx.x * 64 + w * 16 + r;
    short8 afr[4];
    #pragma unroll
    for (int s = 0; s < 4; ++s) {
        float4 a = make_float4(0.f, 0.f, 0.f, 0.f);
        float4 b = make_float4(0.f, 0.f, 0.f, 0.f);
        if (grow < N_NODES) {
            const float4* p = (const float4*)(x + (size_t)grow * HID + (s * 4 + kg) * 8);
            a = p[0]; b = p[1];
        }
        uint4 o;
        o.x = f2bf(a.x) | (f2bf(a.y) << 16);
        o.y = f2bf(a.z) | (f2bf(a.w) << 16);
        o.z = f2bf(b.x) | (f2bf(b.y) << 16);
        o.w = f2bf(b.z) | (f2bf(b.w) << 16);
        afr[s] = *(short8*)&o;
    }

    // flat loop over mi = m*8+nt with one-step register prefetch of W frags
    uint4 wc[4], wn[4];
    #pragma unroll
    for (int s = 0; s < 4; ++s) wc[s] = wtbf[s * 64 + lane];

    #pragma unroll
    for (int mi = 0; mi < 32; ++mi) {
        if (mi < 31) {
            #pragma unroll
            for (int s = 0; s < 4; ++s)
                wn[s] = wtbf[((mi + 1) * 4 + s) * 64 + lane];
        }

        f32x4 acc;
        acc[0]=0.f; acc[1]=0.f; acc[2]=0.f; acc[3]=0.f;
        #pragma unroll
        for (int s = 0; s < 4; ++s)
            acc = __builtin_amdgcn_mfma_f32_16x16x32_bf16(*(short8*)&wc[s], afr[s], acc, 0, 0, 0);

        const int m = mi >> 3, nt = mi & 7;
        if (grow < N_NODES) {
            const float* bias = (m == 0) ? bq : (m == 1) ? bk : (m == 2) ? bv : bs;
            const int col = nt * 16 + kg * 4;
            float4 bi = *(const float4*)(bias + col);
            float vx = acc[0] + bi.x, vy = acc[1] + bi.y;
            float vz = acc[2] + bi.z, vw = acc[3] + bi.w;
            if (m == 1) { vx *= KSCALE_L2E; vy *= KSCALE_L2E;
                          vz *= KSCALE_L2E; vw *= KSCALE_L2E; }
            uint2 pk;
            pk.x = h2u(__builtin_amdgcn_cvt_pkrtz(vx, vy));
            pk.y = h2u(__builtin_amdgcn_cvt_pkrtz(vz, vw));
            unsigned short* dst =
                (m == 0) ? (Qh + (size_t)grow * HID + col) :
                (m == 1) ? (KVh + (size_t)grow * 256 + col) :
                (m == 2) ? (KVh + (size_t)grow * 256 + 128 + col) :
                           (Sh + (size_t)grow * HID + col);
            *(uint2*)dst = pk;
        }

        #pragma unroll
        for (int s = 0; s < 4; ++s) wc[s] = wn[s];
    }
}

// ---------------------------------------------------------------------------
// Fused per-node attention (FP16 packed math): one wave per node; FOUR
// 16-lane edge slots (8 dims/lane), prefetch DISTANCE 2 (3 KV buffers in
// rotation -> 12 gathers in flight per wave). Direct exp2 (K pre-scaled).
// Slot merge on packed regs; skip + LayerNorm fused.
// ---------------------------------------------------------------------------
__global__ __launch_bounds__(256) void node_attn(
    const int* __restrict__ rowptr, const int* __restrict__ csr_src,
    const unsigned short* __restrict__ Qh, const unsigned short* __restrict__ KVh,
    const unsigned short* __restrict__ Sh,
    const float* __restrict__ gamma, const float* __restrict__ beta,
    float* __restrict__ out)
{
    const int tid  = threadIdx.x;
    const int lane = tid & 63;
    const int node = blockIdx.x * 4 + (tid >> 6);
    if (node >= N_NODES) return;

    const int l16 = lane & 15;
    const int es  = lane >> 4;            // edge slot 0..3
    const int j8  = l16 * 8;              // dims j8..j8+7; head = l16>>2

    const int r0 = rowptr[node], r1 = rowptr[node + 1];

    uint4 qp = *(const uint4*)(Qh + (size_t)node * HID + j8);
    const h2 qh0 = u2h(qp.x), qh1 = u2h(qp.y), qh2 = u2h(qp.z), qh3 = u2h(qp.w);

    float den = 0.f;
    h2 ac0 = {0, 0}, ac1 = {0, 0}, ac2 = {0, 0}, ac3 = {0, 0};

    int pA = r0 + es;                     // current
    int pB = pA + 4;                      // +1 iteration
    uint4 kA = {0,0,0,0}, vA = {0,0,0,0}, kB = {0,0,0,0}, vB = {0,0,0,0};
    if (pA < r1) {
        const unsigned short* base = KVh + (size_t)csr_src[pA] * 256;
        kA = *(const uint4*)(base + j8);
        vA = *(const uint4*)(base + 128 + j8);
    }
    if (pB < r1) {
        const unsigned short* base = KVh + (size_t)csr_src[pB] * 256;
        kB = *(const uint4*)(base + j8);
        vB = *(const uint4*)(base + 128 + j8);
    }

    for (int it = r0; it < r1; it += 4) {
        // prefetch distance-2 iteration
        const int pn = pA + 8;
        uint4 kn = {0,0,0,0}, vn = {0,0,0,0};
        if (pn < r1) {
            const unsigned short* base = KVh + (size_t)csr_src[pn] * 256;
            kn = *(const uint4*)(base + j8);
            vn = *(const uint4*)(base + 128 + j8);
        }

        // packed fp16 dot (4 x v_pk_fma_f16) then f32 finish
        h2 d = qh0 * u2h(kA.x);
        d += qh1 * u2h(kA.y);
        d += qh2 * u2h(kA.z);
        d += qh3 * u2h(kA.w);
        float t = (float)d.x + (float)d.y;
        t += __shfl_xor(t, 1);
        t += __shfl_xor(t, 2);              // 4-lane head group complete

        float e = (pA < r1) ? __builtin_amdgcn_exp2f(t) : 0.f;
        den += e;
        _Float16 eh = (_Float16)e;
        h2 e2 = {eh, eh};
        ac0 += e2 * u2h(vA.x);
        ac1 += e2 * u2h(vA.y);
        ac2 += e2 * u2h(vA.z);
        ac3 += e2 * u2h(vA.w);

        // rotate buffers
        pA = pB; pB = pn;
        kA = kB; vA = vB; kB = kn; vB = vn;
    }

    // merge the 4 edge slots (lanes ^16, ^32) on packed regs
    #pragma unroll
    for (int msk = 16; msk <= 32; msk <<= 1) {
        den += __shfl_xor(den, msk);
        ac0 += u2h(__shfl_xor(h2u(ac0), msk));
        ac1 += u2h(__shfl_xor(h2u(ac1), msk));
        ac2 += u2h(__shfl_xor(h2u(ac2), msk));
        ac3 += u2h(__shfl_xor(h2u(ac3), msk));
    }

    float inv = 1.0f / (den + 1e-16f);
    uint4 sp = *(const uint4*)(Sh + (size_t)node * HID + j8);
    const h2 s0 = u2h(sp.x), s1 = u2h(sp.y), s2 = u2h(sp.z), s3 = u2h(sp.w);
    float o0 = (float)ac0.x * inv + (float)s0.x, o1 = (float)ac0.y * inv + (float)s0.y;
    float o2 = (float)ac1.x * inv + (float)s1.x, o3 = (float)ac1.y * inv + (float)s1.y;
    float o4 = (float)ac2.x * inv + (float)s2.x, o5 = (float)ac2.y * inv + (float)s2.y;
    float o6 = (float)ac3.x * inv + (float)s3.x, o7 = (float)ac3.y * inv + (float)s3.y;

    // LayerNorm reduce over 16 lanes (all slots hold identical data now)
    float sum = (o0 + o1) + (o2 + o3) + (o4 + o5) + (o6 + o7);
    float sq  = o0*o0 + o1*o1 + o2*o2 + o3*o3 + o4*o4 + o5*o5 + o6*o6 + o7*o7;
    #pragma unroll
    for (int off = 1; off < 16; off <<= 1) {
        sum += __shfl_xor(sum, off);
        sq  += __shfl_xor(sq, off);
    }
    float mean = sum * (1.0f / 128.0f);
    float var  = sq * (1.0f / 128.0f) - mean * mean;
    float rstd = rsqrtf(var + 1e-5f);

    if (es == 0) {
        float4 g0 = *(const float4*)(gamma + j8);
        float4 g1 = *(const float4*)(gamma + j8 + 4);
        float4 b0 = *(const float4*)(beta + j8);
        float4 b1 = *(const float4*)(beta + j8 + 4);
        float4 w0, w1;
        w0.x = (o0 - mean) * rstd * g0.x + b0.x;
        w0.y = (o1 - mean) * rstd * g0.y + b0.y;
        w0.z = (o2 - mean) * rstd * g0.z + b0.z;
        w0.w = (o3 - mean) * rstd * g0.w + b0.w;
        w1.x = (o4 - mean) * rstd * g1.x + b1.x;
        w1.y = (o5 - mean) * rstd * g1.y + b1.y;
        w1.z = (o6 - mean) * rstd * g1.z + b1.z;
        w1.w = (o7 - mean) * rstd * g1.w + b1.w;
        float* op = out + (size_t)node * HID + j8;
        *(float4*)op = w0;
        *(float4*)(op + 4) = w1;
    }
}

// ---------------------------------------------------------------------------
extern "C" void kernel_launch(void* const* d_in, const int* in_sizes, int n_in,
                              void* d_out, int out_size, void* d_ws, size_t ws_size,
                              hipStream_t stream) {
    const float* x  = (const float*)d_in[0];
    const int*   ei = (const int*)d_in[1];
    const float* Wq = (const float*)d_in[2];
    const float* bq = (const float*)d_in[3];
    const float* Wk = (const float*)d_in[4];
    const float* bk = (const float*)d_in[5];
    const float* Wv = (const float*)d_in[6];
    const float* bv = (const float*)d_in[7];
    const float* Ws = (const float*)d_in[8];
    const float* bs = (const float*)d_in[9];
    const float* gamma = (const float*)d_in[10];
    const float* beta  = (const float*)d_in[11];
    float* out = (float*)d_out;

    // workspace layout (all fp16 feature buffers)
    unsigned short* Qh  = (unsigned short*)d_ws;               // [N,128]
    unsigned short* KVh = Qh + (size_t)N_NODES * HID;          // [N,256]
    unsigned short* Sh  = KVh + (size_t)N_NODES * 256;         // [N,128]
    uint4* wtbf  = (uint4*)(Sh + (size_t)N_NODES * HID);       // [4*8*4*64]
    int* deg     = (int*)(wtbf + 4 * 8 * 4 * 64);
    int* rowptr  = deg + N_NODES;                              // N+1
    int* csr_src = rowptr + (N_NODES + 1);
    int* bsum    = csr_src + N_EDGES;                          // 64

    hipMemsetAsync(deg, 0, N_NODES * sizeof(int), stream);

    const int eblk = (N_EDGES + 255) / 256;                    // 3125
    prep<<<32 + eblk, 256, 0, stream>>>(Wq, Wk, Wv, Ws, wtbf, ei, deg);

    const int nb = (N_NODES + 2047) / 2048;                    // 49
    scan_local<<<nb, 256, 0, stream>>>(deg, rowptr, bsum);
    add_off<<<(N_NODES + 255) / 256, 256, 0, stream>>>(rowptr, bsum);

    fill_proj<<<PROJ_BLOCKS + FILL_BLOCKS, 256, 0, stream>>>(
        ei, rowptr, deg, csr_src, x, wtbf, bq, bk, bv, bs, Qh, KVh, Sh);

    node_attn<<<(N_NODES + 3) / 4, 256, 0, stream>>>(rowptr, csr_src, Qh, KVh, Sh,
                                                     gamma, beta, out);
}

// Round 21
// 185.247 us; speedup vs baseline: 1.3464x; 1.1127x over previous
//
#include <hip/hip_runtime.h>
#include <math.h>

#define N_NODES 100000
#define N_EDGES 800000
#define HID 128
#define HEADS 4
#define HD 32

// 1/sqrt(32) * log2(e), folded into K projection; logits feed exp2 directly
#define KSCALE_L2E 0.2550348554422384f

#define PROJ_BLOCKS 782   // ceil(N_NODES/128), 256 thr each (4 waves x 2x16 rows)
#define FILL_BLOCKS 3125  // ceil(N_EDGES/256)

typedef __attribute__((ext_vector_type(8))) short short8;
typedef __attribute__((ext_vector_type(4))) float f32x4;
typedef _Float16 h2 __attribute__((ext_vector_type(2)));
typedef __fp16 hf2 __attribute__((ext_vector_type(2)));   // cvt_pkrtz return type

__device__ __forceinline__ unsigned int f2bf(float f) {
    unsigned int u = __float_as_uint(f);
    u += 0x7FFFu + ((u >> 16) & 1u);
    return (u >> 16) & 0xFFFFu;   // RNE round to bf16
}
__device__ __forceinline__ h2 u2h(unsigned int u) { return __builtin_bit_cast(h2, u); }
__device__ __forceinline__ unsigned int h2u(h2 h) { return __builtin_bit_cast(unsigned int, h); }
__device__ __forceinline__ unsigned int h2u(hf2 h) { return __builtin_bit_cast(unsigned int, h); }

// ---------------------------------------------------------------------------
// prep: blocks 0..31 convert W fp32 -> bf16 transposed chunks [m][n][kc]
// (for LDS staging); remaining blocks histogram edge destinations.
// ---------------------------------------------------------------------------
__global__ __launch_bounds__(256) void prep(
    const float* __restrict__ Wq, const float* __restrict__ Wk,
    const float* __restrict__ Wv, const float* __restrict__ Ws,
    uint4* __restrict__ wtbf, const int* __restrict__ ei,
    int* __restrict__ deg)
{
    const int b = blockIdx.x;
    if (b < 32) {
        int idx = b * 256 + threadIdx.x;        // [4][128][16]
        int m = idx >> 11, n = (idx >> 4) & 127, kc = idx & 15;
        const float* W = (m == 0) ? Wq : (m == 1) ? Wk : (m == 2) ? Wv : Ws;
        unsigned int h[8];
        #pragma unroll
        for (int j = 0; j < 8; ++j) h[j] = f2bf(W[(kc * 8 + j) * HID + n]);
        uint4 o;
        o.x = h[0] | (h[1] << 16);
        o.y = h[2] | (h[3] << 16);
        o.z = h[4] | (h[5] << 16);
        o.w = h[6] | (h[7] << 16);
        wtbf[idx] = o;
    } else {
        int e = (b - 32) * 256 + threadIdx.x;
        if (e < N_EDGES) atomicAdd(&deg[ei[N_EDGES + e]], 1);
    }
}

// ---------------------------------------------------------------------------
// CSR scan: hierarchical (49 blk local -> per-block offset add).
// ---------------------------------------------------------------------------
__global__ __launch_bounds__(256) void scan_local(const int* __restrict__ deg,
                                                  int* __restrict__ rowptr,
                                                  int* __restrict__ bsum)
{
    __shared__ int wsums[4];
    const int b = blockIdx.x, t = threadIdx.x, lane = t & 63, wid = t >> 6;
    const int base = b * 2048 + t * 8;
    int v[8], s = 0;
    #pragma unroll
    for (int j = 0; j < 8; ++j) {
        int i = base + j;
        v[j] = (i < N_NODES) ? deg[i] : 0;
        s += v[j];
    }
    const int tsum = s;
    int x = tsum;
    #pragma unroll
    for (int off = 1; off < 64; off <<= 1) {
        int t2 = __shfl_up(x, off);
        if (lane >= off) x += t2;
    }
    if (lane == 63) wsums[wid] = x;
    __syncthreads();
    int wpre = 0;
    #pragma unroll
    for (int ww = 0; ww < 4; ++ww) { if (ww < wid) wpre += wsums[ww]; }
    int run = wpre + x - tsum;
    #pragma unroll
    for (int j = 0; j < 8; ++j) {
        int i = base + j;
        if (i < N_NODES) rowptr[i] = run;
        run += v[j];
    }
    if (t == 0) bsum[b] = wsums[0] + wsums[1] + wsums[2] + wsums[3];
}

__global__ __launch_bounds__(256) void add_off(int* __restrict__ rowptr,
                                               const int* __restrict__ bsum)
{
    __shared__ int offs;
    const int t = threadIdx.x;
    const int tgt = blockIdx.x >> 3;       // 2048-node groups / 256-node blocks
    if (t < 64) {
        int v = (t < tgt) ? bsum[t] : 0;
        #pragma unroll
        for (int off = 1; off < 64; off <<= 1) v += __shfl_xor(v, off);
        if (t == 0) offs = v;
    }
    __syncthreads();
    int i = blockIdx.x * 256 + t;
    if (i < N_NODES) rowptr[i] += offs;
    if (blockIdx.x == 0 && t == 0) rowptr[N_NODES] = N_EDGES;
}

// ---------------------------------------------------------------------------
// Fused: blocks 0..PROJ_BLOCKS-1 = MFMA projections, 256 thr / 128 rows each
// (each wave owns TWO 16-row groups; every W fragment feeds 2 MFMAs), ONE W
// staged at a time in 32 KB LDS. Remaining blocks = CSR fill (atomicSub
// countdown on deg -> deg ends zero), packing around the proj blocks.
// ---------------------------------------------------------------------------
__global__ __launch_bounds__(256) void fill_proj(
    const int* __restrict__ ei, const int* __restrict__ rowptr,
    int* __restrict__ deg, int* __restrict__ csr_src,
    const float* __restrict__ x, const uint4* __restrict__ wtbf,
    const float* __restrict__ bq, const float* __restrict__ bk,
    const float* __restrict__ bv, const float* __restrict__ bs,
    unsigned short* __restrict__ Qh, unsigned short* __restrict__ KVh,
    unsigned short* __restrict__ Sh)
{
    __shared__ uint4 wt[2048];          // 32 KB: ONE W matrix at a time

    if (blockIdx.x >= PROJ_BLOCKS) {
        int e = (blockIdx.x - PROJ_BLOCKS) * 256 + threadIdx.x;
        if (e < N_EDGES) {
            int src = ei[e], dst = ei[N_EDGES + e];
            int old = atomicSub(&deg[dst], 1);
            csr_src[rowptr[dst] + old - 1] = src;
        }
        return;
    }

    const int rb   = blockIdx.x * 128;
    const int tid  = threadIdx.x;
    const int lane = tid & 63;
    const int w    = tid >> 6;          // 0..3
    const int r    = lane & 15;
    const int kg   = lane >> 4;

    // this wave's 32 x-rows (two 16-row groups) into bf16 fragments
    const int grow0 = rb + w * 32 + r;
    const int grow1 = grow0 + 16;
    short8 afr[2][4];
    #pragma unroll
    for (int rg = 0; rg < 2; ++rg) {
        const int grow = rg ? grow1 : grow0;
        #pragma unroll
        for (int s = 0; s < 4; ++s) {
            float4 a = make_float4(0.f, 0.f, 0.f, 0.f);
            float4 b = make_float4(0.f, 0.f, 0.f, 0.f);
            if (grow < N_NODES) {
                const float4* p = (const float4*)(x + (size_t)grow * HID + (s * 4 + kg) * 8);
                a = p[0]; b = p[1];
            }
            uint4 o;
            o.x = f2bf(a.x) | (f2bf(a.y) << 16);
            o.y = f2bf(a.z) | (f2bf(a.w) << 16);
            o.z = f2bf(b.x) | (f2bf(b.y) << 16);
            o.w = f2bf(b.z) | (f2bf(b.w) << 16);
            afr[rg][s] = *(short8*)&o;
        }
    }

    #pragma unroll
    for (int m = 0; m < 4; ++m) {
        if (m > 0) __syncthreads();              // prior matrix reads done
        // stage W_m: exactly 2048 uint4 (32 KB), swizzled chunk ^= n&7
        #pragma unroll
        for (int it = 0; it < 8; ++it) {
            int cid = it * 256 + tid;            // [n][kc]
            int kc = cid & 15, n = (cid >> 4) & 127;
            wt[(cid & ~15) | (kc ^ (n & 7))] = wtbf[m * 2048 + cid];
        }
        __syncthreads();

        const float* bias = (m == 0) ? bq : (m == 1) ? bk : (m == 2) ? bv : bs;
        #pragma unroll
        for (int nt = 0; nt < 8; ++nt) {
            const int nrow = nt * 16 + r;
            const uint4* wrow = wt + nrow * 16;
            f32x4 acc0, acc1;
            acc0[0]=0.f; acc0[1]=0.f; acc0[2]=0.f; acc0[3]=0.f;
            acc1[0]=0.f; acc1[1]=0.f; acc1[2]=0.f; acc1[3]=0.f;
            #pragma unroll
            for (int s = 0; s < 4; ++s) {
                short8 bfr = *(const short8*)&wrow[(s * 4 + kg) ^ (nrow & 7)];
                acc0 = __builtin_amdgcn_mfma_f32_16x16x32_bf16(bfr, afr[0][s], acc0, 0, 0, 0);
                acc1 = __builtin_amdgcn_mfma_f32_16x16x32_bf16(bfr, afr[1][s], acc1, 0, 0, 0);
            }
            const int col = nt * 16 + kg * 4;
            float4 bi = *(const float4*)(bias + col);
            #pragma unroll
            for (int rg = 0; rg < 2; ++rg) {
                const int grow = rg ? grow1 : grow0;
                if (grow < N_NODES) {
                    f32x4 acc = rg ? acc1 : acc0;
                    float vx = acc[0] + bi.x, vy = acc[1] + bi.y;
                    float vz = acc[2] + bi.z, vw = acc[3] + bi.w;
                    if (m == 1) { vx *= KSCALE_L2E; vy *= KSCALE_L2E;
                                  vz *= KSCALE_L2E; vw *= KSCALE_L2E; }
                    uint2 pk;
                    pk.x = h2u(__builtin_amdgcn_cvt_pkrtz(vx, vy));
                    pk.y = h2u(__builtin_amdgcn_cvt_pkrtz(vz, vw));
                    unsigned short* dst =
                        (m == 0) ? (Qh + (size_t)grow * HID + col) :
                        (m == 1) ? (KVh + (size_t)grow * 256 + col) :
                        (m == 2) ? (KVh + (size_t)grow * 256 + 128 + col) :
                                   (Sh + (size_t)grow * HID + col);
                    *(uint2*)dst = pk;
                }
            }
        }
    }
}

// ---------------------------------------------------------------------------
// Fused per-node attention (FP16 packed math): one wave per node; FOUR
// 16-lane edge slots (8 dims/lane), prefetch DISTANCE 2 (3 KV buffers in
// rotation -> 12 gathers in flight per wave). Direct exp2 (K pre-scaled).
// Slot merge on packed regs; skip + LayerNorm fused.
// ---------------------------------------------------------------------------
__global__ __launch_bounds__(256) void node_attn(
    const int* __restrict__ rowptr, const int* __restrict__ csr_src,
    const unsigned short* __restrict__ Qh, const unsigned short* __restrict__ KVh,
    const unsigned short* __restrict__ Sh,
    const float* __restrict__ gamma, const float* __restrict__ beta,
    float* __restrict__ out)
{
    const int tid  = threadIdx.x;
    const int lane = tid & 63;
    const int node = blockIdx.x * 4 + (tid >> 6);
    if (node >= N_NODES) return;

    const int l16 = lane & 15;
    const int es  = lane >> 4;            // edge slot 0..3
    const int j8  = l16 * 8;              // dims j8..j8+7; head = l16>>2

    const int r0 = rowptr[node], r1 = rowptr[node + 1];

    uint4 qp = *(const uint4*)(Qh + (size_t)node * HID + j8);
    const h2 qh0 = u2h(qp.x), qh1 = u2h(qp.y), qh2 = u2h(qp.z), qh3 = u2h(qp.w);

    float den = 0.f;
    h2 ac0 = {0, 0}, ac1 = {0, 0}, ac2 = {0, 0}, ac3 = {0, 0};

    int pA = r0 + es;                     // current
    int pB = pA + 4;                      // +1 iteration
    uint4 kA = {0,0,0,0}, vA = {0,0,0,0}, kB = {0,0,0,0}, vB = {0,0,0,0};
    if (pA < r1) {
        const unsigned short* base = KVh + (size_t)csr_src[pA] * 256;
        kA = *(const uint4*)(base + j8);
        vA = *(const uint4*)(base + 128 + j8);
    }
    if (pB < r1) {
        const unsigned short* base = KVh + (size_t)csr_src[pB] * 256;
        kB = *(const uint4*)(base + j8);
        vB = *(const uint4*)(base + 128 + j8);
    }

    for (int it = r0; it < r1; it += 4) {
        // prefetch distance-2 iteration
        const int pn = pA + 8;
        uint4 kn = {0,0,0,0}, vn = {0,0,0,0};
        if (pn < r1) {
            const unsigned short* base = KVh + (size_t)csr_src[pn] * 256;
            kn = *(const uint4*)(base + j8);
            vn = *(const uint4*)(base + 128 + j8);
        }

        // packed fp16 dot (4 x v_pk_fma_f16) then f32 finish
        h2 d = qh0 * u2h(kA.x);
        d += qh1 * u2h(kA.y);
        d += qh2 * u2h(kA.z);
        d += qh3 * u2h(kA.w);
        float t = (float)d.x + (float)d.y;
        t += __shfl_xor(t, 1);
        t += __shfl_xor(t, 2);              // 4-lane head group complete

        float e = (pA < r1) ? __builtin_amdgcn_exp2f(t) : 0.f;
        den += e;
        _Float16 eh = (_Float16)e;
        h2 e2 = {eh, eh};
        ac0 += e2 * u2h(vA.x);
        ac1 += e2 * u2h(vA.y);
        ac2 += e2 * u2h(vA.z);
        ac3 += e2 * u2h(vA.w);

        // rotate buffers
        pA = pB; pB = pn;
        kA = kB; vA = vB; kB = kn; vB = vn;
    }

    // merge the 4 edge slots (lanes ^16, ^32) on packed regs
    #pragma unroll
    for (int msk = 16; msk <= 32; msk <<= 1) {
        den += __shfl_xor(den, msk);
        ac0 += u2h(__shfl_xor(h2u(ac0), msk));
        ac1 += u2h(__shfl_xor(h2u(ac1), msk));
        ac2 += u2h(__shfl_xor(h2u(ac2), msk));
        ac3 += u2h(__shfl_xor(h2u(ac3), msk));
    }

    float inv = 1.0f / (den + 1e-16f);
    uint4 sp = *(const uint4*)(Sh + (size_t)node * HID + j8);
    const h2 s0 = u2h(sp.x), s1 = u2h(sp.y), s2 = u2h(sp.z), s3 = u2h(sp.w);
    float o0 = (float)ac0.x * inv + (float)s0.x, o1 = (float)ac0.y * inv + (float)s0.y;
    float o2 = (float)ac1.x * inv + (float)s1.x, o3 = (float)ac1.y * inv + (float)s1.y;
    float o4 = (float)ac2.x * inv + (float)s2.x, o5 = (float)ac2.y * inv + (float)s2.y;
    float o6 = (float)ac3.x * inv + (float)s3.x, o7 = (float)ac3.y * inv + (float)s3.y;

    // LayerNorm reduce over 16 lanes (all slots hold identical data now)
    float sum = (o0 + o1) + (o2 + o3) + (o4 + o5) + (o6 + o7);
    float sq  = o0*o0 + o1*o1 + o2*o2 + o3*o3 + o4*o4 + o5*o5 + o6*o6 + o7*o7;
    #pragma unroll
    for (int off = 1; off < 16; off <<= 1) {
        sum += __shfl_xor(sum, off);
        sq  += __shfl_xor(sq, off);
    }
    float mean = sum * (1.0f / 128.0f);
    float var  = sq * (1.0f / 128.0f) - mean * mean;
    float rstd = rsqrtf(var + 1e-5f);

    if (es == 0) {
        float4 g0 = *(const float4*)(gamma + j8);
        float4 g1 = *(const float4*)(gamma + j8 + 4);
        float4 b0 = *(const float4*)(beta + j8);
        float4 b1 = *(const float4*)(beta + j8 + 4);
        float4 w0, w1;
        w0.x = (o0 - mean) * rstd * g0.x + b0.x;
        w0.y = (o1 - mean) * rstd * g0.y + b0.y;
        w0.z = (o2 - mean) * rstd * g0.z + b0.z;
        w0.w = (o3 - mean) * rstd * g0.w + b0.w;
        w1.x = (o4 - mean) * rstd * g1.x + b1.x;
        w1.y = (o5 - mean) * rstd * g1.y + b1.y;
        w1.z = (o6 - mean) * rstd * g1.z + b1.z;
        w1.w = (o7 - mean) * rstd * g1.w + b1.w;
        float* op = out + (size_t)node * HID + j8;
        *(float4*)op = w0;
        *(float4*)(op + 4) = w1;
    }
}

// ---------------------------------------------------------------------------
extern "C" void kernel_launch(void* const* d_in, const int* in_sizes, int n_in,
                              void* d_out, int out_size, void* d_ws, size_t ws_size,
                              hipStream_t stream) {
    const float* x  = (const float*)d_in[0];
    const int*   ei = (const int*)d_in[1];
    const float* Wq = (const float*)d_in[2];
    const float* bq = (const float*)d_in[3];
    const float* Wk = (const float*)d_in[4];
    const float* bk = (const float*)d_in[5];
    const float* Wv = (const float*)d_in[6];
    const float* bv = (const float*)d_in[7];
    const float* Ws = (const float*)d_in[8];
    const float* bs = (const float*)d_in[9];
    const float* gamma = (const float*)d_in[10];
    const float* beta  = (const float*)d_in[11];
    float* out = (float*)d_out;

    // workspace layout (all fp16 feature buffers)
    unsigned short* Qh  = (unsigned short*)d_ws;               // [N,128]
    unsigned short* KVh = Qh + (size_t)N_NODES * HID;          // [N,256]
    unsigned short* Sh  = KVh + (size_t)N_NODES * 256;         // [N,128]
    uint4* wtbf  = (uint4*)(Sh + (size_t)N_NODES * HID);       // [4*128*16]
    int* deg     = (int*)(wtbf + 4 * 128 * 16);
    int* rowptr  = deg + N_NODES;                              // N+1
    int* csr_src = rowptr + (N_NODES + 1);
    int* bsum    = csr_src + N_EDGES;                          // 64

    hipMemsetAsync(deg, 0, N_NODES * sizeof(int), stream);

    const int eblk = (N_EDGES + 255) / 256;                    // 3125
    prep<<<32 + eblk, 256, 0, stream>>>(Wq, Wk, Wv, Ws, wtbf, ei, deg);

    const int nb = (N_NODES + 2047) / 2048;                    // 49
    scan_local<<<nb, 256, 0, stream>>>(deg, rowptr, bsum);
    add_off<<<(N_NODES + 255) / 256, 256, 0, stream>>>(rowptr, bsum);

    fill_proj<<<PROJ_BLOCKS + FILL_BLOCKS, 256, 0, stream>>>(
        ei, rowptr, deg, csr_src, x, wtbf, bq, bk, bv, bs, Qh, KVh, Sh);

    node_attn<<<(N_NODES + 3) / 4, 256, 0, stream>>>(rowptr, csr_src, Qh, KVh, Sh,
                                                     gamma, beta, out);
}